// Round 6
// baseline (40.592 us; speedup 1.0000x reference)
//
#include <hip/hip_runtime.h>

typedef __attribute__((ext_vector_type(8)))  __bf16 bf16x8;
typedef __attribute__((ext_vector_type(16))) float  f32x16;
typedef unsigned int uint32;

#define D_IN  128
#define N_OUT 32
#define K129  129
#define WROW  16512          // 128*129 floats per W row
#define KE    144            // extended K for W: col 128 = wlin, 129..143 = 0
#define NT    8              // m-tiles (32 rows) per block = 256-row run
#define XQ_ELEMS (16384 * 128)
#define WQ_ELEMS (32 * 128 * KE)

// slot -> i permutation within each 32-row block: makes each lane's acc rows
// line up with the 8-elem col chunks its own B-fragments hold.
__host__ __device__ __forceinline__ int permSlot(int s) {
    int q = s >> 3, h = (s >> 2) & 1, j = s & 3;
    return 16 * (q >> 1) + 8 * h + 4 * (q & 1) + j;
}

// ---- fused prep: x -> bf16 [16384][128]; W -> bf16 [32][128 slots][144] ----
__global__ void prep(const float* __restrict__ x, const float* __restrict__ W,
                     __bf16* __restrict__ xq, __bf16* __restrict__ Wq) {
    int t = blockIdx.x * 256 + threadIdx.x;          // 1024*256 = 262144 threads
    {
        const float4* s = reinterpret_cast<const float4*>(x) + (size_t)t * 2;
        float4 a = s[0], b = s[1];
        bf16x8 v = { (__bf16)a.x, (__bf16)a.y, (__bf16)a.z, (__bf16)a.w,
                     (__bf16)b.x, (__bf16)b.y, (__bf16)b.z, (__bf16)b.w };
        reinterpret_cast<bf16x8*>(xq)[t] = v;
    }
    for (int e = t; e < WQ_ELEMS; e += 262144) {
        int oi = e / KE, k = e - oi * KE;            // oi = o*128 + slot_g
        int o = oi >> 7, sg = oi & 127;
        int i = (sg & ~31) + permSlot(sg & 31);      // permuted source row
        float v = (k <= D_IN) ? W[o * WROW + i * K129 + k] : 0.f;  // k==128 -> wlin
        Wq[e] = (__bf16)v;
    }
}

// LDS tile: [32 rows][16 chunks of 16B], chunk-XOR swizzled (phys c = log c ^ (r&15)).
// Staged via global_load_lds with pre-swizzled SOURCE (linear dest).
#define STAGE(BUF, T)                                                              \
  do {                                                                             \
    if (PREP) {                                                                    \
      __builtin_amdgcn_global_load_lds(                                            \
        (const __attribute__((address_space(1))) uint32*)                          \
          (xq + ((rbase + (long)(T) * 32 + r0s) * D_IN + c0s * 8)),                \
        (__attribute__((address_space(3))) uint32*)(&tile[BUF][wave * 1024]),      \
        16, 0, 0);                                                                 \
      __builtin_amdgcn_global_load_lds(                                            \
        (const __attribute__((address_space(1))) uint32*)                          \
          (xq + ((rbase + (long)(T) * 32 + r1s) * D_IN + c1s * 8)),                \
        (__attribute__((address_space(3))) uint32*)(&tile[BUF][wave * 1024 + 512]),\
        16, 0, 0);                                                                 \
    } else {                                                                       \
      const float* s0 = x + (rbase + (long)(T) * 32 + r0s) * D_IN + c0s * 8;       \
      const float* s1 = x + (rbase + (long)(T) * 32 + r1s) * D_IN + c1s * 8;       \
      float4 a0 = *(const float4*)s0, a1 = *(const float4*)(s0 + 4);               \
      float4 b0 = *(const float4*)s1, b1 = *(const float4*)(s1 + 4);               \
      bf16x8 v0 = { (__bf16)a0.x,(__bf16)a0.y,(__bf16)a0.z,(__bf16)a0.w,           \
                    (__bf16)a1.x,(__bf16)a1.y,(__bf16)a1.z,(__bf16)a1.w };         \
      bf16x8 v1 = { (__bf16)b0.x,(__bf16)b0.y,(__bf16)b0.z,(__bf16)b0.w,           \
                    (__bf16)b1.x,(__bf16)b1.y,(__bf16)b1.z,(__bf16)b1.w };         \
      *(bf16x8*)&tile[BUF][(size_t)p0 * 8] = v0;                                   \
      *(bf16x8*)&tile[BUF][(size_t)p1 * 8] = v1;                                   \
    }                                                                              \
  } while (0)

// One m-tile: 8 swizzled ds_read_b128 -> 4 blocks x 9 MFMA (setprio-wrapped);
// epilogue dot reuses the SAME B-frag registers (permuted W). Result -> sArr[MT].
#define COMPUTE(BUF, MT)                                                           \
  {                                                                                \
    const char* tb = (const char*)&tile[BUF][0];                                   \
    bf16x8 Bf[8];                                                                  \
    _Pragma("unroll")                                                              \
    for (int ks = 0; ks < 8; ++ks)                                                 \
      Bf[ks] = *reinterpret_cast<const bf16x8*>(tb + laneB[ks]);                   \
    float s = 0.f;                                                                 \
    __builtin_amdgcn_s_setprio(1);                                                 \
    _Pragma("unroll")                                                              \
    for (int ct = 0; ct < 4; ++ct) {                                               \
      f32x16 a;                                                                    \
      _Pragma("unroll")                                                            \
      for (int r = 0; r < 16; ++r) a[r] = 0.f;                                     \
      _Pragma("unroll")                                                            \
      for (int ks = 0; ks < 8; ++ks)                                               \
        a = __builtin_amdgcn_mfma_f32_32x32x16_bf16(A[ct][ks], Bf[ks], a, 0, 0, 0);\
      a = __builtin_amdgcn_mfma_f32_32x32x16_bf16(A[ct][8], B8c, a, 0, 0, 0);      \
      _Pragma("unroll")                                                            \
      for (int q = 0; q < 4; ++q)                                                  \
        _Pragma("unroll")                                                          \
        for (int j = 0; j < 4; ++j)                                                \
          s += a[q * 4 + j] * (float)Bf[2 * ct + (q >> 1)][4 * (q & 1) + j];       \
    }                                                                              \
    __builtin_amdgcn_s_setprio(0);                                                 \
    s += __shfl_xor(s, 32);                                                        \
    sArr[MT] = s;                                                                  \
  }

#define WAITV(N) asm volatile("s_waitcnt vmcnt(" #N ")" ::: "memory")

// Counted-vmcnt pipeline iteration: wait own stage-T loads (leave newer in
// flight), raw barrier (NO vmcnt(0) drain), issue stage T+3 into the buffer
// everyone finished reading at T-1, then compute tile T.
#define ITER(T, VN)                                                                \
  {                                                                                \
    WAITV(VN);                                                                     \
    __builtin_amdgcn_s_barrier();                                                  \
    asm volatile("" ::: "memory");                                                 \
    if ((T) + 3 < NT) STAGE(((T) + 3) & 3, (T) + 3);                               \
    COMPUTE((T) & 3, (T));                                                         \
  }

// Block = 4 waves = 4 o's over one shared 256-row run. Each wave: full 128-i
// for its o (A stationary); x 4-deep double-buffered in LDS, 3 stages in flight.
template<int PREP>
__global__ __launch_bounds__(256, 2) void quad6(
    const float* __restrict__ x, const float* __restrict__ W,
    const __bf16* __restrict__ xq, const __bf16* __restrict__ Wq,
    const float* __restrict__ bias, float* __restrict__ out)
{
    __shared__ __align__(16) __bf16 tile[4][32 * 128];   // 4 x 8KB, swizzled

    const int tid  = threadIdx.x;
    const int lane = tid & 63;
    const int wave = tid >> 6;              // 0..3 = o within group
    const int b32  = lane & 31, hi = lane >> 5;

    // grid 512 = 8 XCD x (8 runs x 8 o-groups): same-XCD blocks share x runs
    const int bid = blockIdx.x;
    const int xcd = bid & 7, idx = bid >> 3;
    const int run = xcd * 8 + (idx & 7);    // 0..63
    const int og  = idx >> 3;               // 0..7
    const int o   = og * 4 + wave;
    const long rbase = (long)run * (NT * 32);
    const float bias_o = bias[o];

    // ---- stationary A fragments: lane -> slot row ct*32 + b32, k = hi*8 + r ----
    bf16x8 A[4][9];
    #pragma unroll
    for (int ct = 0; ct < 4; ++ct) {
        if (PREP) {
            const __bf16* base = Wq + ((size_t)o * 128 + ct * 32 + b32) * KE + hi * 8;
            #pragma unroll
            for (int ks = 0; ks < 9; ++ks)
                A[ct][ks] = *reinterpret_cast<const bf16x8*>(base + ks * 16);
        } else {
            const int i = ct * 32 + permSlot(b32);
            const float* wr = W + (size_t)o * WROW + (size_t)i * K129;
            #pragma unroll
            for (int ks = 0; ks < 8; ++ks) {
                bf16x8 f;
                #pragma unroll
                for (int r = 0; r < 8; ++r) f[r] = (__bf16)wr[ks * 16 + hi * 8 + r];
                A[ct][ks] = f;
            }
            bf16x8 f;
            #pragma unroll
            for (int r = 0; r < 8; ++r) f[r] = (__bf16)0.f;
            if (hi == 0) f[0] = (__bf16)wr[128];         // wlin at k=128
            A[ct][8] = f;
        }
    }

    // constant ks=8 B fragment: x~[b,128]=1, rest 0
    bf16x8 B8c;
    #pragma unroll
    for (int r = 0; r < 8; ++r) B8c[r] = (__bf16)0.f;
    if (hi == 0) B8c[0] = (__bf16)1.0f;

    // staging mapping: thread -> phys chunks {wave*128+lane, +64}; src pre-swizzled
    const int p0 = wave * 128 + lane;
    const int r0s = p0 >> 4, c0s = (p0 & 15) ^ (r0s & 15);
    const int p1 = p0 + 64;
    const int r1s = p1 >> 4, c1s = (p1 & 15) ^ (r1s & 15);

    // swizzled ds_read byte offsets (row = b32, logical chunk 2ks+hi)
    const int rm = b32 & 15;
    int laneB[8];
    #pragma unroll
    for (int ks = 0; ks < 8; ++ks)
        laneB[ks] = b32 * 256 + (((ks * 2 + hi) ^ rm) << 4);

    float sArr[NT];

    // prologue: 3 stages in flight
    STAGE(0, 0);
    STAGE(1, 1);
    STAGE(2, 2);

    ITER(0, 4); ITER(1, 4); ITER(2, 4); ITER(3, 4);
    ITER(4, 4); ITER(5, 4); ITER(6, 2); ITER(7, 0);

    // ---- deferred store pass (fire and forget) ----
    if (hi == 0) {
        #pragma unroll
        for (int mt = 0; mt < NT; ++mt)
            out[(rbase + (long)mt * 32 + b32) * N_OUT + o] = sArr[mt] + bias_o;
    }
}

extern "C" void kernel_launch(void* const* d_in, const int* in_sizes, int n_in,
                              void* d_out, int out_size, void* d_ws, size_t ws_size,
                              hipStream_t stream) {
    const float* x    = (const float*)d_in[0];
    const float* W    = (const float*)d_in[1];
    const float* bias = (const float*)d_in[2];
    float* out = (float*)d_out;

    const size_t need = (size_t)(XQ_ELEMS + WQ_ELEMS) * sizeof(__bf16);  // ~5.4 MB
    if (ws_size >= need) {
        __bf16* xq = (__bf16*)d_ws;
        __bf16* Wq = xq + XQ_ELEMS;
        prep<<<1024, 256, 0, stream>>>(x, W, xq, Wq);
        quad6<1><<<512, 256, 0, stream>>>(x, W, xq, Wq, bias, out);
    } else {
        quad6<0><<<512, 256, 0, stream>>>(x, W, (const __bf16*)nullptr,
                                          (const __bf16*)nullptr, bias, out);
    }
}